// Round 1
// baseline (2557.286 us; speedup 1.0000x reference)
//
#include <hip/hip_runtime.h>

// VQ: B=200000 rows of D=128 fp32; K=1024 codebook rows.
// Output: quant_x [B*D] fp32, then codes [B] written as fp32 values.
// Strategy: lane = row. x row held entirely in VGPRs (128 regs). Codebook
// address is wave-uniform -> compiler should emit scalar (s_load) reads via
// the constant cache, making the inner loop pure v_fma_f32 (VALU-bound,
// ~157 TF fp32 ceiling -> ~335 us floor for 52.4 GFLOP).

#define DDIM 128
#define KCODES 1024

__global__ void csq_kernel(const float* __restrict__ cb, float* __restrict__ csq) {
    int k = blockIdx.x * blockDim.x + threadIdx.x;
    if (k >= KCODES) return;
    const float* __restrict__ c = cb + (long)k * DDIM;
    float s0 = 0.f, s1 = 0.f, s2 = 0.f, s3 = 0.f;
#pragma unroll
    for (int d = 0; d < DDIM; d += 4) {
        s0 = fmaf(c[d + 0], c[d + 0], s0);
        s1 = fmaf(c[d + 1], c[d + 1], s1);
        s2 = fmaf(c[d + 2], c[d + 2], s2);
        s3 = fmaf(c[d + 3], c[d + 3], s3);
    }
    csq[k] = (s0 + s1) + (s2 + s3);
}

__launch_bounds__(256)
__global__ void vq_kernel(const float* __restrict__ x, const float* __restrict__ cb,
                          const float* __restrict__ csq, float* __restrict__ quant,
                          float* __restrict__ codes, int B) {
    const long row = (long)blockIdx.x * blockDim.x + threadIdx.x;
    const bool active = row < B;
    const long r = active ? row : 0;

    // Load this lane's x row into registers (32 x float4 = 128 VGPRs).
    float xr[DDIM];
    const float4* __restrict__ xp = (const float4*)(x + r * DDIM);
#pragma unroll
    for (int i = 0; i < DDIM / 4; ++i) {
        float4 v = xp[i];
        xr[4 * i + 0] = v.x;
        xr[4 * i + 1] = v.y;
        xr[4 * i + 2] = v.z;
        xr[4 * i + 3] = v.w;
    }

    // ||x||^2 with 4 partial chains (ILP + closer to BLAS-style pairwise sums).
    float s0 = 0.f, s1 = 0.f, s2 = 0.f, s3 = 0.f;
#pragma unroll
    for (int d = 0; d < DDIM; d += 4) {
        s0 = fmaf(xr[d + 0], xr[d + 0], s0);
        s1 = fmaf(xr[d + 1], xr[d + 1], s1);
        s2 = fmaf(xr[d + 2], xr[d + 2], s2);
        s3 = fmaf(xr[d + 3], xr[d + 3], s3);
    }
    const float x_sq = (s0 + s1) + (s2 + s3);

    float best = 3.4e38f;
    int bidx = 0;
    for (int k = 0; k < KCODES; ++k) {
        const float* __restrict__ c = cb + (long)k * DDIM;  // wave-uniform address
        float a0 = 0.f, a1 = 0.f, a2 = 0.f, a3 = 0.f;
#pragma unroll
        for (int d = 0; d < DDIM; d += 4) {
            a0 = fmaf(xr[d + 0], c[d + 0], a0);
            a1 = fmaf(xr[d + 1], c[d + 1], a1);
            a2 = fmaf(xr[d + 2], c[d + 2], a2);
            a3 = fmaf(xr[d + 3], c[d + 3], a3);
        }
        const float dot = (a0 + a1) + (a2 + a3);
        // Same association as reference: (x_sq - 2*dot) + c_sq. (2*dot is exact,
        // so fmaf(-2, dot, x_sq) == fl(x_sq - 2*dot).)
        const float dist = fmaf(-2.0f, dot, x_sq) + csq[k];
        if (dist < best) { best = dist; bidx = k; }  // strict < == first-index tie-break
    }

    if (active) {
        const float4* __restrict__ cc = (const float4*)(cb + (long)bidx * DDIM);
        float4* __restrict__ qp = (float4*)(quant + row * DDIM);
#pragma unroll
        for (int i = 0; i < DDIM / 4; ++i) qp[i] = cc[i];
        codes[row] = (float)bidx;
    }
}

extern "C" void kernel_launch(void* const* d_in, const int* in_sizes, int n_in,
                              void* d_out, int out_size, void* d_ws, size_t ws_size,
                              hipStream_t stream) {
    const float* x  = (const float*)d_in[0];
    const float* cb = (const float*)d_in[1];
    const int B = in_sizes[0] / DDIM;  // 200000

    float* quant = (float*)d_out;
    float* codes = (float*)d_out + (size_t)B * DDIM;
    float* csq   = (float*)d_ws;  // 1024 floats of scratch (recomputed every launch)

    csq_kernel<<<(KCODES + 255) / 256, 256, 0, stream>>>(cb, csq);

    const int blocks = (B + 255) / 256;
    vq_kernel<<<blocks, 256, 0, stream>>>(x, cb, csq, quant, codes, B);
}